// Round 14
// baseline (35.257 us; speedup 1.0000x reference)
//
#include <hip/hip_runtime.h>
#include <hip/hip_bf16.h>
#include <cstdint>

// ProkBertAttention: sliding-window (+-64) attention with RoPE.
// B=4, S=2048, H=12, D=64. fp32 in/out, bf16 MFMA compute.
// Mask input (d_in[3]) ignored: band structure computed analytically.
//
// Round 14: TWO-KERNEL decomposition. Monolith pinned at 27.2-28.0us across
// six structural variants (no pipe >35%); top counter = VALUBusy, mostly
// RoPE/convert staging recomputed 3x per K row. Split:
//  k1 prokbert_prep: streaming pass qkv(f32) -> ws: K^ (RoPE'd bf16,
//     [hh][s][64], 16B-chunk XOR(s&7) baked in) + V^ (key-paired u32,
//     [hh][kp][64], column rotated by 8*((kp>>1)&3) mod 64 for 2-way banks).
//     Pure elementwise, no barriers -> fillBuffer-class BW (87% measured).
//  k2 prokbert_attn2: stages K^/V^ with 12 plain 16B copies/thread (no
//     converts; swizzles pre-baked), Q RoPE inline, one barrier, then
//     QK->softmax->PV->store identical to r13's proven data path.
// Fallback: if ws_size < 25.2MB, run the verbatim r13 mono kernel.

typedef short bf16x8 __attribute__((ext_vector_type(8)));
typedef float f32x4  __attribute__((ext_vector_type(4)));
typedef uint32_t u32x4 __attribute__((ext_vector_type(4)));

#define SLEN   2048
#define NHEAD  12
#define NBATCH 4
#define HD     64
#define WHALF  64
#define QT     64          // queries per block (4 waves x 16)
#define KROWS  192
#define NKC    9           // per-wave key chunks (144-key span)
// scale * log2(e) = (1/8) * 1.4426950408889634 (scores in log2 units)
#define QSCALE 0.18033688011112042f

__device__ __forceinline__ uint32_t cvt_pk(float lo, float hi) {
    // dst[15:0] = bf16(lo), dst[31:16] = bf16(hi); RNE (gfx950)
    uint32_t r;
    asm("v_cvt_pk_bf16_f32 %0, %1, %2" : "=v"(r) : "v"(lo), "v"(hi));
    return r;
}

// ===================== k1: prep (RoPE'd K^, paired V^) =====================
// K jobs: 48*2048*4 = 393216 (blocks 0..1535). job=(row,c4): c4 owns
//   d = c4*8..+7 AND +32 (full RoPE pair). Write chunks XOR-swizzled by s&7.
// V jobs: 48*1024*8 = 393216 (blocks 1536..3071). job=(kpg,c8): 8 dims of
//   pair kp; cell = (bf16 V[2kp][d], V[2kp+1][d]); col rotated by
//   8*((kp>>1)&3) mod 64 (bijective; spreads PV read banks 2-way).
__global__ __launch_bounds__(256) void prokbert_prep(
        const float* __restrict__ qkv, const float* __restrict__ cosT,
        const float* __restrict__ sinT, short* __restrict__ khat,
        uint32_t* __restrict__ vhat)
{
    const int job = blockIdx.x * 256 + threadIdx.x;
    if (job < 48 * 2048 * 4) {
        const int row = job >> 2, c4 = job & 3, d0 = c4 * 8;
        const int s = row & 2047, hh = row >> 11;
        const int b = hh / NHEAD, h = hh % NHEAD;
        const size_t kbase = (((size_t)(b * SLEN + s) * 3 + 1) * NHEAD + h) * HD;
        const f32x4* gxl = (const f32x4*)(qkv + kbase + d0);
        const f32x4* gxh = (const f32x4*)(qkv + kbase + d0 + 32);
        const f32x4* gc  = (const f32x4*)(cosT + s * HD + d0);  // cos[d+32]==cos[d]
        const f32x4* gs  = (const f32x4*)(sinT + s * HD + d0);
        const f32x4 xl0 = gxl[0], xl1 = gxl[1], xh0 = gxh[0], xh1 = gxh[1];
        const f32x4 c0 = gc[0], c1 = gc[1], s0v = gs[0], s1v = gs[1];
        u32x4 klo, khi;
        // RoPE: lo[d] = x[d]*c - x[d+32]*s ; hi[d+32] = x[d+32]*c + x[d]*s
        klo[0] = cvt_pk(xl0[0]*c0[0]-xh0[0]*s0v[0], xl0[1]*c0[1]-xh0[1]*s0v[1]);
        klo[1] = cvt_pk(xl0[2]*c0[2]-xh0[2]*s0v[2], xl0[3]*c0[3]-xh0[3]*s0v[3]);
        klo[2] = cvt_pk(xl1[0]*c1[0]-xh1[0]*s1v[0], xl1[1]*c1[1]-xh1[1]*s1v[1]);
        klo[3] = cvt_pk(xl1[2]*c1[2]-xh1[2]*s1v[2], xl1[3]*c1[3]-xh1[3]*s1v[3]);
        khi[0] = cvt_pk(xh0[0]*c0[0]+xl0[0]*s0v[0], xh0[1]*c0[1]+xl0[1]*s0v[1]);
        khi[1] = cvt_pk(xh0[2]*c0[2]+xl0[2]*s0v[2], xh0[3]*c0[3]+xl0[3]*s0v[3]);
        khi[2] = cvt_pk(xh1[0]*c1[0]+xl1[0]*s1v[0], xh1[1]*c1[1]+xl1[1]*s1v[1]);
        khi[3] = cvt_pk(xh1[2]*c1[2]+xl1[2]*s1v[2], xh1[3]*c1[3]+xl1[3]*s1v[3]);
        const int sw = s & 7;
        *(u32x4*)&khat[(size_t)row * 64 + ((c4 ^ sw) << 3)]       = klo;
        *(u32x4*)&khat[(size_t)row * 64 + (((c4 + 4) ^ sw) << 3)] = khi;
    } else {
        const int j2 = job - 48 * 2048 * 4;
        const int kpg = j2 >> 3, c8 = j2 & 7, d0 = c8 * 8;
        const int kp = kpg & 1023, hh = kpg >> 10;
        const int b = hh / NHEAD, h = hh % NHEAD;
        const int s0 = 2 * kp, s1 = s0 + 1;
        const f32x4* g0 = (const f32x4*)(qkv +
            (((size_t)(b * SLEN + s0) * 3 + 2) * NHEAD + h) * HD + d0);
        const f32x4* g1 = (const f32x4*)(qkv +
            (((size_t)(b * SLEN + s1) * 3 + 2) * NHEAD + h) * HD + d0);
        const f32x4 va0 = g0[0], va1 = g0[1], vb0 = g1[0], vb1 = g1[1];
        u32x4 w0, w1;
        w0[0] = cvt_pk(va0[0], vb0[0]); w0[1] = cvt_pk(va0[1], vb0[1]);
        w0[2] = cvt_pk(va0[2], vb0[2]); w0[3] = cvt_pk(va0[3], vb0[3]);
        w1[0] = cvt_pk(va1[0], vb1[0]); w1[1] = cvt_pk(va1[1], vb1[1]);
        w1[2] = cvt_pk(va1[2], vb1[2]); w1[3] = cvt_pk(va1[3], vb1[3]);
        const int col0 = (d0 + 8 * ((kp >> 1) & 3)) & 63;   // mult of 8: no straddle
        *(u32x4*)&vhat[(size_t)kpg * 64 + col0]     = w0;
        *(u32x4*)&vhat[(size_t)kpg * 64 + col0 + 4] = w1;
    }
}

// ===================== k2: attention from K^/V^ =====================
__global__ __launch_bounds__(256, 3) void prokbert_attn2(
        const float* __restrict__ qkv, const float* __restrict__ cosT,
        const float* __restrict__ sinT, const short* __restrict__ khat,
        const uint32_t* __restrict__ vhat, float* __restrict__ out)
{
    __shared__ __align__(16) short    sK2[KROWS * 64];   // 24,576 B, XOR(rr&7)
    __shared__ __align__(16) uint32_t sV2[96 * 64];      // 24,576 B, rotated cols

    const int tid = threadIdx.x;

    // ---- XCD-aware block swizzle (1536 = 8 XCDs x 192, bijective) ----
    const int bid = blockIdx.x;
    const int gid = (bid & 7) * 192 + (bid >> 3);
    const int qt = gid & 31;
    const int hh = gid >> 5;
    const int h = hh % NHEAD, b = hh / NHEAD;

    const int q0 = qt * QT;
    const int kstart = q0 - WHALF;
    const int kps = kstart / 2;      // even, may be negative

    const int wv = tid >> 6;
    const int lane = tid & 63;
    const int r = lane & 15, g = lane >> 4;
    const int rx = r & 7;
    const int qrow = q0 + wv * 16 + r;

    // ---- staging loads: 6 K-chunks + 6 V-chunks per wave (1KB each) ----
    // K chunk ch covers global rows kstart+8ch..+8 (all-in or all-out of
    // [0,2048) since kstart%64==0); OOB -> zeros (score 0 -> e=1, fixed
    // analytically; V=0). V chunk covers kp kps+4ch..+4 likewise.
    u32x4 kreg[6], vreg[6];
    #pragma unroll
    for (int it = 0; it < 6; ++it) {
        const int ch = wv * 6 + it;
        const int r0 = kstart + ch * 8;
        const int kp0 = kps + ch * 4;
        const u32x4 z = {0, 0, 0, 0};
        kreg[it] = ((unsigned)r0 <= 2040u)
            ? *(const u32x4*)&khat[((size_t)hh * SLEN + r0) * 64 + lane * 8]
            : z;
        vreg[it] = ((unsigned)kp0 <= 1020u)
            ? *(const u32x4*)&vhat[((size_t)hh * 1024 + kp0) * 64 + lane * 4]
            : z;
    }

    // ---- Q load + RoPE + pack (overlaps staging-load latency) ----
    bf16x8 qf0, qf1;           // k-slots: d = g*8+j and 32+g*8+j
    {
        const size_t qb = (((size_t)(b * SLEN + qrow) * 3 + 0) * NHEAD + h) * HD;
        const f32x4* ga  = (const f32x4*)(qkv + qb + g * 8);
        const f32x4* gb  = (const f32x4*)(qkv + qb + 32 + g * 8);
        const f32x4* gc0 = (const f32x4*)(cosT + (size_t)qrow * HD + g * 8);
        const f32x4* gs0 = (const f32x4*)(sinT + (size_t)qrow * HD + g * 8);
        const f32x4 qa0 = ga[0], qa1 = ga[1], qb0 = gb[0], qb1 = gb[1];
        const f32x4 qc0 = gc0[0], qc1 = gc0[1], qs0 = gs0[0], qs1 = gs0[1];
        u32x4 w0, w1;
        w0[0] = cvt_pk((qa0[0]*qc0[0]-qb0[0]*qs0[0])*QSCALE, (qa0[1]*qc0[1]-qb0[1]*qs0[1])*QSCALE);
        w0[1] = cvt_pk((qa0[2]*qc0[2]-qb0[2]*qs0[2])*QSCALE, (qa0[3]*qc0[3]-qb0[3]*qs0[3])*QSCALE);
        w0[2] = cvt_pk((qa1[0]*qc1[0]-qb1[0]*qs1[0])*QSCALE, (qa1[1]*qc1[1]-qb1[1]*qs1[1])*QSCALE);
        w0[3] = cvt_pk((qa1[2]*qc1[2]-qb1[2]*qs1[2])*QSCALE, (qa1[3]*qc1[3]-qb1[3]*qs1[3])*QSCALE);
        w1[0] = cvt_pk((qb0[0]*qc0[0]+qa0[0]*qs0[0])*QSCALE, (qb0[1]*qc0[1]+qa0[1]*qs0[1])*QSCALE);
        w1[1] = cvt_pk((qb0[2]*qc0[2]+qa0[2]*qs0[2])*QSCALE, (qb0[3]*qc0[3]+qa0[3]*qs0[3])*QSCALE);
        w1[2] = cvt_pk((qb1[0]*qc1[0]+qa1[0]*qs1[0])*QSCALE, (qb1[1]*qc1[1]+qa1[1]*qs1[1])*QSCALE);
        w1[3] = cvt_pk((qb1[2]*qc1[2]+qa1[2]*qs1[2])*QSCALE, (qb1[3]*qc1[3]+qa1[3]*qs1[3])*QSCALE);
        qf0 = __builtin_bit_cast(bf16x8, w0);
        qf1 = __builtin_bit_cast(bf16x8, w1);
    }

    // ---- staging writes (b128, contiguous 1KB per wave-chunk) ----
    #pragma unroll
    for (int it = 0; it < 6; ++it) {
        const int ch = wv * 6 + it;
        *(u32x4*)&sK2[ch * 512 + lane * 8] = kreg[it];
        *(u32x4*)&sV2[ch * 256 + lane * 4] = vreg[it];
    }
    __syncthreads();   // the only barrier

    // ===== fused QK^T -> mask -> exp -> P-pack (deferred norm) =====
    // S^T = mfma(K_chunk, Q): C row = key-in-chunk = 4g+i, C col = query = r.
    u32x4 paw[5];
    float sum = 0.f;
    const int tg = 4 * g;
    #pragma unroll
    for (int kc = 0; kc < NKC; ++kc) {
        const int row = wv * 16 + kc * 16 + r;
        const bf16x8 ka0 = *(const bf16x8*)&sK2[row * 64 + ((g ^ rx) << 3)];
        const bf16x8 ka1 = *(const bf16x8*)&sK2[row * 64 + (((g + 4) ^ rx) << 3)];
        f32x4 c = {0.f, 0.f, 0.f, 0.f};
        c = __builtin_amdgcn_mfma_f32_16x16x32_bf16(ka0, qf0, c, 0, 0, 0);
        c = __builtin_amdgcn_mfma_f32_16x16x32_bf16(ka1, qf1, c, 0, 0, 0);
        f32x4 e;
        #pragma unroll
        for (int i = 0; i < 4; ++i) {
            float ev = exp2f(c[i]);   // scores in log2 units
            if (kc == 0) ev = (tg + i >= r) ? ev : 0.f;
            if (kc == 8) ev = (tg + i <= r) ? ev : 0.f;
            e[i] = ev;
            sum += ev;
        }
        const uint32_t wlo = cvt_pk(e[0], e[1]);
        const uint32_t whi = cvt_pk(e[2], e[3]);
        if ((kc & 1) == 0) { paw[kc >> 1][0] = wlo; paw[kc >> 1][1] = whi; }
        else               { paw[kc >> 1][2] = wlo; paw[kc >> 1][3] = whi; }
    }
    paw[4][2] = 0; paw[4][3] = 0;

    sum += __shfl_xor(sum, 16);
    sum += __shfl_xor(sum, 32);
    const int oob = max(0, WHALF - qrow) + max(0, qrow - (SLEN - 1 - WHALF));
    const float inv = 1.f / (sum - (float)oob);

    // ===== O = P x V: rotated-col u32 reads (col const per lane: 2-way banks) =====
    // k-slot map key(g,j) = kb*32 + (j>>2)*16 + 4g + (j&3) -> local pairs
    // W+{0,1,8,9}, W = wv*8 + kb*16 + 2g. Rotate (kp>>1)&3 == g for all four.
    f32x4 oacc[4] = {{0,0,0,0},{0,0,0,0},{0,0,0,0},{0,0,0,0}};
    #pragma unroll
    for (int kb = 0; kb < 5; ++kb) {
        const bf16x8 pa = __builtin_bit_cast(bf16x8, paw[kb]);
        const int W = wv * 8 + kb * 16 + 2 * g;
        #pragma unroll
        for (int dc = 0; dc < 4; ++dc) {
            const int col = (dc * 16 + r + 8 * g) & 63;
            u32x4 w;
            w[0] = sV2[(W + 0) * 64 + col];
            w[1] = sV2[(W + 1) * 64 + col];
            if (kb < 4) {
                w[2] = sV2[(W + 8) * 64 + col];
                w[3] = sV2[(W + 9) * 64 + col];
            } else {
                w[2] = 0; w[3] = 0;            // pa hi == 0; avoid OOB read
            }
            const bf16x8 vbf = __builtin_bit_cast(bf16x8, w);
            oacc[dc] = __builtin_amdgcn_mfma_f32_16x16x32_bf16(pa, vbf, oacc[dc], 0, 0, 0);
        }
    }

    // ---- store (C row = query = g*4+i, col = d = r), deferred norm ----
    #pragma unroll
    for (int i = 0; i < 4; ++i) {
        const float iq = __shfl(inv, g * 4 + i);
        const int qg = q0 + wv * 16 + g * 4 + i;
        float* orow = out + (((size_t)(b * SLEN + qg)) * NHEAD + h) * HD + r;
        orow[0]  = oacc[0][i] * iq;
        orow[16] = oacc[1][i] * iq;
        orow[32] = oacc[2][i] * iq;
        orow[48] = oacc[3][i] * iq;
    }
}

// ===================== fallback: r13 mono (proven 27.9us) =====================
#define VSTM   68
#define VROWSM 96

__global__ __launch_bounds__(256, 3) void prokbert_attn_mono(
        const float* __restrict__ qkv, const float* __restrict__ cosT,
        const float* __restrict__ sinT, float* __restrict__ out)
{
    __shared__ __align__(16) short    sK[KROWS * 64];
    __shared__ __align__(16) uint32_t sV[VROWSM * VSTM];

    const int tid = threadIdx.x;
    const int bid = blockIdx.x;
    const int gid = (bid & 7) * 192 + (bid >> 3);
    const int qt = gid & 31;
    const int hh = gid >> 5;
    const int h = hh % NHEAD, b = hh / NHEAD;
    const int q0 = qt * QT;
    const int kstart = q0 - WHALF;
    const int wv = tid >> 6;
    const int lane = tid & 63;
    const int r = lane & 15, g = lane >> 4;
    const int rx = r & 7;
    const int qrow = q0 + wv * 16 + r;

    f32x4 va[3][2], vb[3][2];
    #pragma unroll
    for (int it = 0; it < 3; ++it) {
        const int j = tid + it * 256;
        const int kp = j >> 3, dd = (j & 7) * 8;
        const int s0 = kstart + 2 * kp, s1 = s0 + 1;
        const f32x4 z = {0.f, 0.f, 0.f, 0.f};
        if ((unsigned)s0 < SLEN) {
            const f32x4* g0 = (const f32x4*)(qkv +
                (((size_t)(b * SLEN + s0) * 3 + 2) * NHEAD + h) * HD + dd);
            va[it][0] = g0[0]; va[it][1] = g0[1];
        } else { va[it][0] = z; va[it][1] = z; }
        if ((unsigned)s1 < SLEN) {
            const f32x4* g1 = (const f32x4*)(qkv +
                (((size_t)(b * SLEN + s1) * 3 + 2) * NHEAD + h) * HD + dd);
            vb[it][0] = g1[0]; vb[it][1] = g1[1];
        } else { vb[it][0] = z; vb[it][1] = z; }
    }

    const int rrb = tid >> 2, c4 = tid & 3, d0 = c4 * 8;
#define LOADK(IT, S) \
    f32x4 xl0##S, xl1##S, xh0##S, xh1##S, cc0##S, cc1##S, ss0##S, ss1##S; \
    { \
        const int s = kstart + rrb + (IT) * 64; \
        if ((unsigned)s < SLEN) { \
            const size_t kbase = (((size_t)(b * SLEN + s) * 3 + 1) * NHEAD + h) * HD; \
            const f32x4* gxl = (const f32x4*)(qkv + kbase + d0); \
            const f32x4* gxh = (const f32x4*)(qkv + kbase + d0 + 32); \
            const f32x4* gc  = (const f32x4*)(cosT + s * HD + d0); \
            const f32x4* gs  = (const f32x4*)(sinT + s * HD + d0); \
            xl0##S = gxl[0]; xl1##S = gxl[1]; \
            xh0##S = gxh[0]; xh1##S = gxh[1]; \
            cc0##S = gc[0];  cc1##S = gc[1]; \
            ss0##S = gs[0];  ss1##S = gs[1]; \
        } else { \
            const f32x4 z = {0.f, 0.f, 0.f, 0.f}; \
            xl0##S = z; xl1##S = z; xh0##S = z; xh1##S = z; \
            cc0##S = z; cc1##S = z; ss0##S = z; ss1##S = z; \
        } \
    }
#define CONVSTOREK(IT, S) \
    { \
        const int rr = rrb + (IT) * 64; \
        u32x4 klo, khi; \
        klo[0] = cvt_pk(xl0##S[0]*cc0##S[0]-xh0##S[0]*ss0##S[0], xl0##S[1]*cc0##S[1]-xh0##S[1]*ss0##S[1]); \
        klo[1] = cvt_pk(xl0##S[2]*cc0##S[2]-xh0##S[2]*ss0##S[2], xl0##S[3]*cc0##S[3]-xh0##S[3]*ss0##S[3]); \
        klo[2] = cvt_pk(xl1##S[0]*cc1##S[0]-xh1##S[0]*ss1##S[0], xl1##S[1]*cc1##S[1]-xh1##S[1]*ss1##S[1]); \
        klo[3] = cvt_pk(xl1##S[2]*cc1##S[2]-xh1##S[2]*ss1##S[2], xl1##S[3]*cc1##S[3]-xh1##S[3]*ss1##S[3]); \
        khi[0] = cvt_pk(xh0##S[0]*cc0##S[0]+xl0##S[0]*ss0##S[0], xh0##S[1]*cc0##S[1]+xl0##S[1]*ss0##S[1]); \
        khi[1] = cvt_pk(xh0##S[2]*cc0##S[2]+xl0##S[2]*ss0##S[2], xh0##S[3]*cc0##S[3]+xl0##S[3]*ss0##S[3]); \
        khi[2] = cvt_pk(xh1##S[0]*cc1##S[0]+xl1##S[0]*ss1##S[0], xh1##S[1]*cc1##S[1]+xl1##S[1]*ss1##S[1]); \
        khi[3] = cvt_pk(xh1##S[2]*cc1##S[2]+xl1##S[2]*ss1##S[2], xh1##S[3]*cc1##S[3]+xl1##S[3]*ss1##S[3]); \
        const int sw = rr & 7; \
        *(u32x4*)&sK[rr * 64 + ((c4 ^ sw) << 3)]       = klo; \
        *(u32x4*)&sK[rr * 64 + (((c4 + 4) ^ sw) << 3)] = khi; \
    }
    {
        LOADK(0, a)
        LOADK(1, bb)
        CONVSTOREK(0, a)
        LOADK(2, cc)
        CONVSTOREK(1, bb)
        CONVSTOREK(2, cc)
    }
#undef LOADK
#undef CONVSTOREK

    bf16x8 qf0, qf1;
    {
        const size_t qb = (((size_t)(b * SLEN + qrow) * 3 + 0) * NHEAD + h) * HD;
        const f32x4* ga  = (const f32x4*)(qkv + qb + g * 8);
        const f32x4* gb  = (const f32x4*)(qkv + qb + 32 + g * 8);
        const f32x4* gc0 = (const f32x4*)(cosT + (size_t)qrow * HD + g * 8);
        const f32x4* gs0 = (const f32x4*)(sinT + (size_t)qrow * HD + g * 8);
        f32x4 qa0 = ga[0], qa1 = ga[1], qb0 = gb[0], qb1 = gb[1];
        f32x4 qc0 = gc0[0], qc1 = gc0[1], qs0 = gs0[0], qs1 = gs0[1];
        u32x4 w0, w1;
        w0[0] = cvt_pk((qa0[0]*qc0[0]-qb0[0]*qs0[0])*QSCALE, (qa0[1]*qc0[1]-qb0[1]*qs0[1])*QSCALE);
        w0[1] = cvt_pk((qa0[2]*qc0[2]-qb0[2]*qs0[2])*QSCALE, (qa0[3]*qc0[3]-qb0[3]*qs0[3])*QSCALE);
        w0[2] = cvt_pk((qa1[0]*qc1[0]-qb1[0]*qs1[0])*QSCALE, (qa1[1]*qc1[1]-qb1[1]*qs1[1])*QSCALE);
        w0[3] = cvt_pk((qa1[2]*qc1[2]-qb1[2]*qs1[2])*QSCALE, (qa1[3]*qc1[3]-qb1[3]*qs1[3])*QSCALE);
        w1[0] = cvt_pk((qb0[0]*qc0[0]+qa0[0]*qs0[0])*QSCALE, (qb0[1]*qc0[1]+qa0[1]*qs0[1])*QSCALE);
        w1[1] = cvt_pk((qb0[2]*qc0[2]+qa0[2]*qs0[2])*QSCALE, (qb0[3]*qc0[3]+qa0[3]*qs0[3])*QSCALE);
        w1[2] = cvt_pk((qb1[0]*qc1[0]+qa1[0]*qs1[0])*QSCALE, (qb1[1]*qc1[1]+qa1[1]*qs1[1])*QSCALE);
        w1[3] = cvt_pk((qb1[2]*qc1[2]+qa1[2]*qs1[2])*QSCALE, (qb1[3]*qc1[3]+qa1[3]*qs1[3])*QSCALE);
        qf0 = __builtin_bit_cast(bf16x8, w0);
        qf1 = __builtin_bit_cast(bf16x8, w1);
    }

    #pragma unroll
    for (int it = 0; it < 3; ++it) {
        const int j = tid + it * 256;
        const int kp = j >> 3, dd = (j & 7) * 8;
        u32x4 w0, w1;
        w0[0] = cvt_pk(va[it][0][0], vb[it][0][0]);
        w0[1] = cvt_pk(va[it][0][1], vb[it][0][1]);
        w0[2] = cvt_pk(va[it][0][2], vb[it][0][2]);
        w0[3] = cvt_pk(va[it][0][3], vb[it][0][3]);
        w1[0] = cvt_pk(va[it][1][0], vb[it][1][0]);
        w1[1] = cvt_pk(va[it][1][1], vb[it][1][1]);
        w1[2] = cvt_pk(va[it][1][2], vb[it][1][2]);
        w1[3] = cvt_pk(va[it][1][3], vb[it][1][3]);
        *(u32x4*)&sV[kp * VSTM + dd]     = w0;
        *(u32x4*)&sV[kp * VSTM + dd + 4] = w1;
    }
    __syncthreads();

    u32x4 paw[5];
    float sum = 0.f;
    const int tg = 4 * g;
    #pragma unroll
    for (int kc = 0; kc < NKC; ++kc) {
        const int row = wv * 16 + kc * 16 + r;
        const bf16x8 ka0 = *(const bf16x8*)&sK[row * 64 + ((g ^ rx) << 3)];
        const bf16x8 ka1 = *(const bf16x8*)&sK[row * 64 + (((g + 4) ^ rx) << 3)];
        f32x4 c = {0.f, 0.f, 0.f, 0.f};
        c = __builtin_amdgcn_mfma_f32_16x16x32_bf16(ka0, qf0, c, 0, 0, 0);
        c = __builtin_amdgcn_mfma_f32_16x16x32_bf16(ka1, qf1, c, 0, 0, 0);
        f32x4 e;
        #pragma unroll
        for (int i = 0; i < 4; ++i) {
            float ev = exp2f(c[i]);
            if (kc == 0) ev = (tg + i >= r) ? ev : 0.f;
            if (kc == 8) ev = (tg + i <= r) ? ev : 0.f;
            e[i] = ev;
            sum += ev;
        }
        const uint32_t wlo = cvt_pk(e[0], e[1]);
        const uint32_t whi = cvt_pk(e[2], e[3]);
        if ((kc & 1) == 0) { paw[kc >> 1][0] = wlo; paw[kc >> 1][1] = whi; }
        else               { paw[kc >> 1][2] = wlo; paw[kc >> 1][3] = whi; }
    }
    paw[4][2] = 0; paw[4][3] = 0;

    sum += __shfl_xor(sum, 16);
    sum += __shfl_xor(sum, 32);
    const int oob = max(0, WHALF - qrow) + max(0, qrow - (SLEN - 1 - WHALF));
    const float inv = 1.f / (sum - (float)oob);

    const uint32_t* vptr = &sV[(wv * 8 + 2 * g) * VSTM + r];
    f32x4 oacc[4] = {{0,0,0,0},{0,0,0,0},{0,0,0,0},{0,0,0,0}};
    #pragma unroll
    for (int kb = 0; kb < 5; ++kb) {
        const bf16x8 pa = __builtin_bit_cast(bf16x8, paw[kb]);
        #pragma unroll
        for (int dc = 0; dc < 4; ++dc) {
            const int base = kb * 16 * VSTM + dc * 16;
            u32x4 w;
            w[0] = vptr[base];
            w[1] = vptr[base + VSTM];
            if (kb < 4) {
                w[2] = vptr[base + 8 * VSTM];
                w[3] = vptr[base + 9 * VSTM];
            } else {
                w[2] = 0; w[3] = 0;
            }
            const bf16x8 vbf = __builtin_bit_cast(bf16x8, w);
            oacc[dc] = __builtin_amdgcn_mfma_f32_16x16x32_bf16(pa, vbf, oacc[dc], 0, 0, 0);
        }
    }

    #pragma unroll
    for (int i = 0; i < 4; ++i) {
        const float iq = __shfl(inv, g * 4 + i);
        const int qg = q0 + wv * 16 + g * 4 + i;
        float* orow = out + (((size_t)(b * SLEN + qg)) * NHEAD + h) * HD + r;
        orow[0]  = oacc[0][i] * iq;
        orow[16] = oacc[1][i] * iq;
        orow[32] = oacc[2][i] * iq;
        orow[48] = oacc[3][i] * iq;
    }
}

extern "C" void kernel_launch(void* const* d_in, const int* in_sizes, int n_in,
                              void* d_out, int out_size, void* d_ws, size_t ws_size,
                              hipStream_t stream) {
    const float* qkv  = (const float*)d_in[0];
    const float* cosT = (const float*)d_in[1];
    const float* sinT = (const float*)d_in[2];
    // d_in[3] = mask: unused (band structure computed analytically)
    float* out = (float*)d_out;
    const size_t KHAT_BYTES = (size_t)48 * 2048 * 64 * 2;   // 12,582,912
    const size_t VHAT_BYTES = (size_t)48 * 1024 * 64 * 4;   // 12,582,912
    if (ws_size >= KHAT_BYTES + VHAT_BYTES) {
        short*    khat = (short*)d_ws;
        uint32_t* vhat = (uint32_t*)((char*)d_ws + KHAT_BYTES);
        hipLaunchKernelGGL(prokbert_prep, dim3(3072), dim3(256), 0, stream,
                           qkv, cosT, sinT, khat, vhat);
        hipLaunchKernelGGL(prokbert_attn2, dim3(1536), dim3(256), 0, stream,
                           qkv, cosT, sinT, khat, vhat, out);
    } else {
        hipLaunchKernelGGL(prokbert_attn_mono, dim3(1536), dim3(256), 0, stream,
                           qkv, cosT, sinT, out);
    }
}

// Round 15
// 27.630 us; speedup vs baseline: 1.2761x; 1.2761x over previous
//
#include <hip/hip_runtime.h>
#include <hip/hip_bf16.h>
#include <cstdint>

// ProkBertAttention: sliding-window (+-64) attention with RoPE.
// B=4, S=2048, H=12, D=64. fp32 in/out, bf16 MFMA compute.
// Mask input (d_in[3]) ignored: band structure computed analytically.
//
// Round 15 = round 12 (best: 27.196us) + s_setprio(1) around the compute
// stretch (QK->softmax->PV). Round-14 decomposition regressed (35.3us:
// 50MB ws round-trip + serial k1->k2 dependency cost more than the 3x
// staging-RoPE recompute it saved) -> reverted. T5 rationale: 3 independent
// blocks/CU at skewed phases; prioritizing compute-phase waves over
// staging-phase waves is the measured m191 attn case (+4-7%).
// Structure: 512thr, QT=128, two-phase shared LDS (K then V-pairs,
// 3 barriers), pipelined K staging, Q-after-K, K stride 144B (write ~2-way
// banks), fused QK->mask->exp->pack, analytic OOB denominator fix,
// deferred norm, kb=4 lo-only PV (NaN fix), XCD swizzle, 768 blocks = 3/CU.
// Known-bad: (256,6) mis-compiles (VGPR=40 + spill, r8/r11); two-kernel
// split regresses (r14).

typedef short bf16x8 __attribute__((ext_vector_type(8)));
typedef float f32x4  __attribute__((ext_vector_type(4)));
typedef uint32_t u32x4 __attribute__((ext_vector_type(4)));

#define SLEN   2048
#define NHEAD  12
#define NBATCH 4
#define HD     64
#define WHALF  64
#define QT     128         // queries per block (8 waves x 16)
#define KROWS  256         // QT + 2*WHALF
#define NKC    9           // per-wave key chunks (144-key span)
#define KSTR   72          // K row stride in shorts (144B: quad 9r+g, 2-way)
#define VST    68          // V-pair row stride in dwords
#define VROWS  128         // key-pairs (max kp read = 127, exact)
// scale * log2(e) = (1/8) * 1.4426950408889634 (scores in log2 units)
#define QSCALE 0.18033688011112042f

// Phase 1: sbuf holds K bf16 [256 rows][72 stride] (36,864 B), plain layout.
// Phase 2: sbuf holds V key-paired u32 [128][68] (34,816 B), cell[kp][d] =
//          (bf16 V[2kp][d], V[2kp+1][d]).
// LDS alloc = 36,864 B -> 3 blocks/CU (24 waves) with launch_bounds(512,6).

__device__ __forceinline__ uint32_t cvt_pk(float lo, float hi) {
    // dst[15:0] = bf16(lo), dst[31:16] = bf16(hi); RNE (gfx950)
    uint32_t r;
    asm("v_cvt_pk_bf16_f32 %0, %1, %2" : "=v"(r) : "v"(lo), "v"(hi));
    return r;
}

__global__ __launch_bounds__(512, 6) void prokbert_attn(
        const float* __restrict__ qkv, const float* __restrict__ cosT,
        const float* __restrict__ sinT, float* __restrict__ out)
{
    __shared__ __align__(16) uint32_t sbuf[KROWS * KSTR / 2];   // 9216 dwords
    short* sKp = (short*)sbuf;

    const int tid = threadIdx.x;

    // ---- XCD-aware block swizzle (768 blocks = 8 XCDs x 96, bijective) ----
    const int bid = blockIdx.x;
    const int gid = (bid & 7) * 96 + (bid >> 3);
    const int qt = gid & 15;
    const int hh = gid >> 4;          // 0..47 = b*12 + h
    const int h = hh % NHEAD, b = hh / NHEAD;

    const int q0 = qt * QT;
    const int kstart = q0 - WHALF;

    const int wv = tid >> 6;
    const int lane = tid & 63;
    const int r = lane & 15, g = lane >> 4;
    const int qrow = q0 + wv * 16 + r;

    // ================= phase 1: K staging, 2-deep pipelined =================
    // job (rr, c4) owns d = c4*8..+7 AND +32; rr = rrb + it*128, it = 0,1.
    const int rrb = tid >> 2, c4 = tid & 3, d0 = c4 * 8;

#define LOADK(IT, S) \
    f32x4 xl0##S, xl1##S, xh0##S, xh1##S, cc0##S, cc1##S, ss0##S, ss1##S; \
    { \
        const int s = kstart + rrb + (IT) * 128; \
        if ((unsigned)s < SLEN) { \
            const size_t kbase = (((size_t)(b * SLEN + s) * 3 + 1) * NHEAD + h) * HD; \
            const f32x4* gxl = (const f32x4*)(qkv + kbase + d0); \
            const f32x4* gxh = (const f32x4*)(qkv + kbase + d0 + 32); \
            const f32x4* gc  = (const f32x4*)(cosT + s * HD + d0); \
            const f32x4* gs  = (const f32x4*)(sinT + s * HD + d0); \
            xl0##S = gxl[0]; xl1##S = gxl[1]; \
            xh0##S = gxh[0]; xh1##S = gxh[1]; \
            cc0##S = gc[0];  cc1##S = gc[1]; \
            ss0##S = gs[0];  ss1##S = gs[1]; \
        } else { \
            const f32x4 z = {0.f, 0.f, 0.f, 0.f}; \
            xl0##S = z; xl1##S = z; xh0##S = z; xh1##S = z; \
            cc0##S = z; cc1##S = z; ss0##S = z; ss1##S = z; \
        } \
    }

#define CONVSTOREK(IT, S) \
    { \
        const int rr = rrb + (IT) * 128; \
        u32x4 klo, khi; \
        /* RoPE: lo[d] = x[d]*c - x[d+32]*s ; hi[d+32] = x[d+32]*c + x[d]*s */ \
        klo[0] = cvt_pk(xl0##S[0] * cc0##S[0] - xh0##S[0] * ss0##S[0], \
                        xl0##S[1] * cc0##S[1] - xh0##S[1] * ss0##S[1]); \
        klo[1] = cvt_pk(xl0##S[2] * cc0##S[2] - xh0##S[2] * ss0##S[2], \
                        xl0##S[3] * cc0##S[3] - xh0##S[3] * ss0##S[3]); \
        klo[2] = cvt_pk(xl1##S[0] * cc1##S[0] - xh1##S[0] * ss1##S[0], \
                        xl1##S[1] * cc1##S[1] - xh1##S[1] * ss1##S[1]); \
        klo[3] = cvt_pk(xl1##S[2] * cc1##S[2] - xh1##S[2] * ss1##S[2], \
                        xl1##S[3] * cc1##S[3] - xh1##S[3] * ss1##S[3]); \
        khi[0] = cvt_pk(xh0##S[0] * cc0##S[0] + xl0##S[0] * ss0##S[0], \
                        xh0##S[1] * cc0##S[1] + xl0##S[1] * ss0##S[1]); \
        khi[1] = cvt_pk(xh0##S[2] * cc0##S[2] + xl0##S[2] * ss0##S[2], \
                        xh0##S[3] * cc0##S[3] + xl0##S[3] * ss0##S[3]); \
        khi[2] = cvt_pk(xh1##S[0] * cc1##S[0] + xl1##S[0] * ss1##S[0], \
                        xh1##S[1] * cc1##S[1] + xl1##S[1] * ss1##S[1]); \
        khi[3] = cvt_pk(xh1##S[2] * cc1##S[2] + xl1##S[2] * ss1##S[2], \
                        xh1##S[3] * cc1##S[3] + xl1##S[3] * ss1##S[3]); \
        *(u32x4*)&sKp[rr * KSTR + d0]      = klo; \
        *(u32x4*)&sKp[rr * KSTR + 32 + d0] = khi; \
    }

    {
        LOADK(0, a)            // issue batch 0
        LOADK(1, bb)           // issue batch 1 (in flight over batch-0 convert)
        CONVSTOREK(0, a)       // convert+store batch 0 (frees regs)
        CONVSTOREK(1, bb)
    }
#undef LOADK
#undef CONVSTOREK

    // ---- Q load + RoPE + pack (after K staging: K regs dead here) ----
    bf16x8 qf0, qf1;           // k-slots: d = g*8+j and 32+g*8+j
    {
        const size_t qb = (((size_t)(b * SLEN + qrow) * 3 + 0) * NHEAD + h) * HD;
        const f32x4* ga  = (const f32x4*)(qkv + qb + g * 8);
        const f32x4* gb  = (const f32x4*)(qkv + qb + 32 + g * 8);
        const f32x4* gc0 = (const f32x4*)(cosT + (size_t)qrow * HD + g * 8);  // == cos[32+..]
        const f32x4* gs0 = (const f32x4*)(sinT + (size_t)qrow * HD + g * 8);
        f32x4 qa0 = ga[0], qa1 = ga[1], qb0 = gb[0], qb1 = gb[1];
        f32x4 qc0 = gc0[0], qc1 = gc0[1], qs0 = gs0[0], qs1 = gs0[1];
        u32x4 w0, w1;
        w0[0] = cvt_pk((qa0[0] * qc0[0] - qb0[0] * qs0[0]) * QSCALE,
                       (qa0[1] * qc0[1] - qb0[1] * qs0[1]) * QSCALE);
        w0[1] = cvt_pk((qa0[2] * qc0[2] - qb0[2] * qs0[2]) * QSCALE,
                       (qa0[3] * qc0[3] - qb0[3] * qs0[3]) * QSCALE);
        w0[2] = cvt_pk((qa1[0] * qc1[0] - qb1[0] * qs1[0]) * QSCALE,
                       (qa1[1] * qc1[1] - qb1[1] * qs1[1]) * QSCALE);
        w0[3] = cvt_pk((qa1[2] * qc1[2] - qb1[2] * qs1[2]) * QSCALE,
                       (qa1[3] * qc1[3] - qb1[3] * qs1[3]) * QSCALE);
        w1[0] = cvt_pk((qb0[0] * qc0[0] + qa0[0] * qs0[0]) * QSCALE,
                       (qb0[1] * qc0[1] + qa0[1] * qs0[1]) * QSCALE);
        w1[1] = cvt_pk((qb0[2] * qc0[2] + qa0[2] * qs0[2]) * QSCALE,
                       (qb0[3] * qc0[3] + qa0[3] * qs0[3]) * QSCALE);
        w1[2] = cvt_pk((qb1[0] * qc1[0] + qa1[0] * qs1[0]) * QSCALE,
                       (qb1[1] * qc1[1] + qa1[1] * qs1[1]) * QSCALE);
        w1[3] = cvt_pk((qb1[2] * qc1[2] + qa1[2] * qs1[2]) * QSCALE,
                       (qb1[3] * qc1[3] + qa1[3] * qs1[3]) * QSCALE);
        qf0 = __builtin_bit_cast(bf16x8, w0);
        qf1 = __builtin_bit_cast(bf16x8, w1);
    }
    __syncthreads();   // bar1: K staged

    // ===== compute stretch: boost this wave's issue priority (T5) =====
    __builtin_amdgcn_s_setprio(1);

    // ===== fused QK^T -> mask -> exp -> P-pack (deferred norm: no sum pass) =====
    // S^T = mfma(K_chunk, Q): C row = key-in-chunk = 4g+i, C col = query = r.
    // Band mask only at kc=0 (4g+i<r) and kc=8 (4g+i>r); OOB rows give score
    // 0 -> e=1, V=0: denominator fixed analytically below.
    // paw k-slot map: key(g,j) = kb*32 + (j>>2)*16 + 4g + (j&3).
    u32x4 paw[5];
    float sum = 0.f;
    const int tg = 4 * g;
    #pragma unroll
    for (int kc = 0; kc < NKC; ++kc) {
        const int row = wv * 16 + kc * 16 + r;
        const bf16x8 ka0 = *(const bf16x8*)&sKp[row * KSTR + g * 8];
        const bf16x8 ka1 = *(const bf16x8*)&sKp[row * KSTR + 32 + g * 8];
        f32x4 c = {0.f, 0.f, 0.f, 0.f};
        c = __builtin_amdgcn_mfma_f32_16x16x32_bf16(ka0, qf0, c, 0, 0, 0);
        c = __builtin_amdgcn_mfma_f32_16x16x32_bf16(ka1, qf1, c, 0, 0, 0);
        f32x4 e;
        #pragma unroll
        for (int i = 0; i < 4; ++i) {
            float ev = exp2f(c[i]);   // scores already in log2 units
            if (kc == 0) ev = (tg + i >= r) ? ev : 0.f;
            if (kc == 8) ev = (tg + i <= r) ? ev : 0.f;
            e[i] = ev;
            sum += ev;
        }
        const uint32_t wlo = cvt_pk(e[0], e[1]);
        const uint32_t whi = cvt_pk(e[2], e[3]);
        if ((kc & 1) == 0) { paw[kc >> 1][0] = wlo; paw[kc >> 1][1] = whi; }
        else               { paw[kc >> 1][2] = wlo; paw[kc >> 1][3] = whi; }
    }
    paw[4][2] = 0; paw[4][3] = 0;

    sum += __shfl_xor(sum, 16);
    sum += __shfl_xor(sum, 32);
    const int oob = max(0, WHALF - qrow) + max(0, qrow - (SLEN - 1 - WHALF));
    const float inv = 1.f / (sum - (float)oob);

    __builtin_amdgcn_s_setprio(0);   // staging phase: normal priority

    // ================= phase 2: V loads (latency hides under bar2) =========
    const int vkp = tid >> 2, vdb = tid & 3, vd0 = vdb * 16;
    const int s0 = kstart + 2 * vkp, s1 = s0 + 1;
    f32x4 va[4], vb4[4];
    {
        const f32x4 z = {0.f, 0.f, 0.f, 0.f};
        if ((unsigned)s0 < SLEN) {
            const f32x4* g0 = (const f32x4*)(qkv +
                (((size_t)(b * SLEN + s0) * 3 + 2) * NHEAD + h) * HD + vd0);
            va[0] = g0[0]; va[1] = g0[1]; va[2] = g0[2]; va[3] = g0[3];
        } else { va[0] = z; va[1] = z; va[2] = z; va[3] = z; }
        if ((unsigned)s1 < SLEN) {
            const f32x4* g1 = (const f32x4*)(qkv +
                (((size_t)(b * SLEN + s1) * 3 + 2) * NHEAD + h) * HD + vd0);
            vb4[0] = g1[0]; vb4[1] = g1[1]; vb4[2] = g1[2]; vb4[3] = g1[3];
        } else { vb4[0] = z; vb4[1] = z; vb4[2] = z; vb4[3] = z; }
    }
    __syncthreads();   // bar2: all K reads done; sbuf free for V

    #pragma unroll
    for (int u = 0; u < 4; ++u) {
        u32x4 dw;
        dw[0] = cvt_pk(va[u][0], vb4[u][0]);
        dw[1] = cvt_pk(va[u][1], vb4[u][1]);
        dw[2] = cvt_pk(va[u][2], vb4[u][2]);
        dw[3] = cvt_pk(va[u][3], vb4[u][3]);
        *(u32x4*)&sbuf[vkp * VST + vd0 + u * 4] = dw;
    }
    __syncthreads();   // bar3: V staged

    // ===== compute stretch 2: PV under raised priority =====
    __builtin_amdgcn_s_setprio(1);

    // ================= O = P x V (paired-key u32 reads) =================
    // kb<4: keys kb*32 + {0,1,2,3,16,17,18,19} + 4g (pairs +0,+1,+8,+9).
    // kb=4: lo half only (hi pa==0 -> w[2]=w[3]=0, no LDS read; max kp=127).
    const uint32_t* vptr = &sbuf[(wv * 8 + 2 * g) * VST + r];
    f32x4 oacc[4] = {{0,0,0,0},{0,0,0,0},{0,0,0,0},{0,0,0,0}};
    #pragma unroll
    for (int kb = 0; kb < 5; ++kb) {
        const bf16x8 pa = __builtin_bit_cast(bf16x8, paw[kb]);
        #pragma unroll
        for (int dc = 0; dc < 4; ++dc) {
            const int base = kb * 16 * VST + dc * 16;
            u32x4 w;
            w[0] = vptr[base];                 // keys kb*32+4g, +1
            w[1] = vptr[base + VST];           // +2, +3
            if (kb < 4) {
                w[2] = vptr[base + 8 * VST];   // +16, +17
                w[3] = vptr[base + 9 * VST];   // +18, +19
            } else {
                w[2] = 0; w[3] = 0;            // pa hi == 0; avoid OOB read
            }
            const bf16x8 vb = __builtin_bit_cast(bf16x8, w);
            oacc[dc] = __builtin_amdgcn_mfma_f32_16x16x32_bf16(pa, vb, oacc[dc], 0, 0, 0);
        }
    }

    __builtin_amdgcn_s_setprio(0);

    // ---- store (C row = query = g*4+i, col = d = r), deferred norm ----
    #pragma unroll
    for (int i = 0; i < 4; ++i) {
        const float iq = __shfl(inv, g * 4 + i);   // inv depends only on lane&15
        const int qg = q0 + wv * 16 + g * 4 + i;
        float* orow = out + (((size_t)(b * SLEN + qg)) * NHEAD + h) * HD + r;
        orow[0]  = oacc[0][i] * iq;
        orow[16] = oacc[1][i] * iq;
        orow[32] = oacc[2][i] * iq;
        orow[48] = oacc[3][i] * iq;
    }
}

extern "C" void kernel_launch(void* const* d_in, const int* in_sizes, int n_in,
                              void* d_out, int out_size, void* d_ws, size_t ws_size,
                              hipStream_t stream) {
    const float* qkv  = (const float*)d_in[0];
    const float* cosT = (const float*)d_in[1];
    const float* sinT = (const float*)d_in[2];
    // d_in[3] = mask: unused (band structure computed analytically)
    float* out = (float*)d_out;
    dim3 grid(16 * NHEAD * NBATCH);   // 768 = 3 blocks/CU x 256 CUs, no tail
    dim3 block(512);
    hipLaunchKernelGGL(prokbert_attn, grid, block, 0, stream, qkv, cosT, sinT, out);
}

// Round 16
// 26.618 us; speedup vs baseline: 1.3245x; 1.0380x over previous
//
#include <hip/hip_runtime.h>
#include <hip/hip_bf16.h>
#include <cstdint>

// ProkBertAttention: sliding-window (+-64) attention with RoPE.
// B=4, S=2048, H=12, D=64. fp32 in/out, bf16 MFMA compute.
// Mask input (d_in[3]) ignored: band structure computed analytically.
//
// Round 16: the 6-chains/CU geometry (256thr, QT=64, grid 1536 = 6/CU,
// launch_bounds(256,8)) with SPILL-PROOF staging: every prior (256,6+)
// attempt (r8/r10/r11) spilled because staging batched 48+ regs under a
// tight cap (VGPR=40 + WRITE 39-101MB signature). This round: strictly
// serial staging (load->convert->store per job in closed scopes, Q in two
// half-chunks, V after bar2) -> peak live ~55 regs <= 64 cap. Latency
// hiding comes from TLP (24 waves, 6 independent chains) instead of ILP.
// Data path byte-identical to r11/r12 (passed): two-phase shared LDS
// (K [192][64] XOR, V [96][68] pairs), fused QK->mask->exp->pack, analytic
// OOB denominator fix, kb=4 lo-only PV, deferred norm, XCD swizzle.
// Ledger: r12 27.20us (best); decomposition 35.3 (r14); setprio neutral
// (r15); bank-conflict fix neutral (r12 vs r9).

typedef short bf16x8 __attribute__((ext_vector_type(8)));
typedef float f32x4  __attribute__((ext_vector_type(4)));
typedef uint32_t u32x4 __attribute__((ext_vector_type(4)));

#define SLEN   2048
#define NHEAD  12
#define NBATCH 4
#define HD     64
#define WHALF  64
#define QT     64          // queries per block (4 waves x 16)
#define KROWS  192         // QT + 2*WHALF
#define NKC    9           // per-wave key chunks (144-key span)
#define VST    68          // V-pair row stride in dwords
#define VROWS  96          // key-pairs (max kp read = 95: kb=4 lo-only)
// scale * log2(e) = (1/8) * 1.4426950408889634 (scores in log2 units)
#define QSCALE 0.18033688011112042f

// Phase 1: sbuf holds K bf16 [192][64] (24,576 B), 16B-chunk XOR (c^(rr&7)).
// Phase 2: sbuf holds V key-paired u32 [96][68] (26,112 B), cell[kp][d] =
//          (bf16 V[2kp][d], V[2kp+1][d]).
// LDS alloc = 26,112 B; 6 blocks x 26,112 = 156,672 <= 163,840 -> 6/CU
// when VGPR <= 64 (launch_bounds(256,8): 8 waves/EU cap).

__device__ __forceinline__ uint32_t cvt_pk(float lo, float hi) {
    // dst[15:0] = bf16(lo), dst[31:16] = bf16(hi); RNE (gfx950)
    uint32_t r;
    asm("v_cvt_pk_bf16_f32 %0, %1, %2" : "=v"(r) : "v"(lo), "v"(hi));
    return r;
}

__global__ __launch_bounds__(256, 8) void prokbert_attn(
        const float* __restrict__ qkv, const float* __restrict__ cosT,
        const float* __restrict__ sinT, float* __restrict__ out)
{
    __shared__ __align__(16) uint32_t sbuf[VROWS * VST];
    short* sKp = (short*)sbuf;

    const int tid = threadIdx.x;

    // ---- XCD-aware block swizzle (1536 blocks = 8 XCDs x 192, bijective) ----
    const int bid = blockIdx.x;
    const int gid = (bid & 7) * 192 + (bid >> 3);
    const int qt = gid & 31;          // 32 q-tiles per (b,h)
    const int hh = gid >> 5;          // 0..47 = b*12 + h
    const int h = hh % NHEAD, b = hh / NHEAD;

    const int q0 = qt * QT;
    const int kstart = q0 - WHALF;

    const int wv = tid >> 6;
    const int lane = tid & 63;
    const int r = lane & 15, g = lane >> 4;
    const int rx = r & 7;
    const int qrow = q0 + wv * 16 + r;

    // ========== phase 1: K staging, 3 jobs, STRICTLY SERIAL ==========
    // job (rr, c4) owns d = c4*8..+7 AND +32; rr = rrb + it*64.
    // Each job's regs live only inside its scope (~30 regs peak).
    const int rrb = tid >> 2, c4 = tid & 3, d0 = c4 * 8;

    #pragma unroll
    for (int it = 0; it < 3; ++it) {
        const int rr = rrb + it * 64;
        const int s = kstart + rr;
        u32x4 klo = {0, 0, 0, 0}, khi = {0, 0, 0, 0};
        if ((unsigned)s < SLEN) {
            const size_t kbase = (((size_t)(b * SLEN + s) * 3 + 1) * NHEAD + h) * HD;
            const f32x4* gxl = (const f32x4*)(qkv + kbase + d0);
            const f32x4* gxh = (const f32x4*)(qkv + kbase + d0 + 32);
            const f32x4* gc  = (const f32x4*)(cosT + s * HD + d0);  // cos[d+32]==cos[d]
            const f32x4* gs  = (const f32x4*)(sinT + s * HD + d0);
            const f32x4 xl0 = gxl[0], xl1 = gxl[1];
            const f32x4 xh0 = gxh[0], xh1 = gxh[1];
            const f32x4 c0 = gc[0], c1 = gc[1];
            const f32x4 s0 = gs[0], s1 = gs[1];
            // RoPE: lo[d] = x[d]*c - x[d+32]*s ; hi[d+32] = x[d+32]*c + x[d]*s
            klo[0] = cvt_pk(xl0[0]*c0[0]-xh0[0]*s0[0], xl0[1]*c0[1]-xh0[1]*s0[1]);
            klo[1] = cvt_pk(xl0[2]*c0[2]-xh0[2]*s0[2], xl0[3]*c0[3]-xh0[3]*s0[3]);
            klo[2] = cvt_pk(xl1[0]*c1[0]-xh1[0]*s1[0], xl1[1]*c1[1]-xh1[1]*s1[1]);
            klo[3] = cvt_pk(xl1[2]*c1[2]-xh1[2]*s1[2], xl1[3]*c1[3]-xh1[3]*s1[3]);
            khi[0] = cvt_pk(xh0[0]*c0[0]+xl0[0]*s0[0], xh0[1]*c0[1]+xl0[1]*s0[1]);
            khi[1] = cvt_pk(xh0[2]*c0[2]+xl0[2]*s0[2], xh0[3]*c0[3]+xl0[3]*s0[3]);
            khi[2] = cvt_pk(xh1[0]*c1[0]+xl1[0]*s1[0], xh1[1]*c1[1]+xl1[1]*s1[1]);
            khi[3] = cvt_pk(xh1[2]*c1[2]+xl1[2]*s1[2], xh1[3]*c1[3]+xl1[3]*s1[3]);
        }
        const int sw = rr & 7;
        *(u32x4*)&sKp[rr * 64 + ((c4 ^ sw) << 3)]       = klo;
        *(u32x4*)&sKp[rr * 64 + (((c4 + 4) ^ sw) << 3)] = khi;
    }

    // ---- Q load + RoPE + pack, two half-chunks (16 regs live each) ----
    bf16x8 qf0, qf1;           // k-slots: d = g*8+j and 32+g*8+j
    {
        u32x4 w0, w1;
        const size_t qb = (((size_t)(b * SLEN + qrow) * 3 + 0) * NHEAD + h) * HD;
        #pragma unroll
        for (int p = 0; p < 2; ++p) {
            const int dq = g * 8 + p * 4;
            const f32x4 qa = *(const f32x4*)(qkv + qb + dq);
            const f32x4 qbv = *(const f32x4*)(qkv + qb + 32 + dq);
            const f32x4 qc = *(const f32x4*)(cosT + (size_t)qrow * HD + dq);
            const f32x4 qs = *(const f32x4*)(sinT + (size_t)qrow * HD + dq);
            w0[2*p]   = cvt_pk((qa[0]*qc[0]-qbv[0]*qs[0])*QSCALE,
                               (qa[1]*qc[1]-qbv[1]*qs[1])*QSCALE);
            w0[2*p+1] = cvt_pk((qa[2]*qc[2]-qbv[2]*qs[2])*QSCALE,
                               (qa[3]*qc[3]-qbv[3]*qs[3])*QSCALE);
            w1[2*p]   = cvt_pk((qbv[0]*qc[0]+qa[0]*qs[0])*QSCALE,
                               (qbv[1]*qc[1]+qa[1]*qs[1])*QSCALE);
            w1[2*p+1] = cvt_pk((qbv[2]*qc[2]+qa[2]*qs[2])*QSCALE,
                               (qbv[3]*qc[3]+qa[3]*qs[3])*QSCALE);
        }
        qf0 = __builtin_bit_cast(bf16x8, w0);
        qf1 = __builtin_bit_cast(bf16x8, w1);
    }
    __syncthreads();   // bar1: K staged

    // ===== fused QK^T -> mask -> exp -> P-pack (deferred norm) =====
    // S^T = mfma(K_chunk, Q): C row = key-in-chunk = 4g+i, C col = query = r.
    // Band mask only at kc=0 (4g+i<r) and kc=8 (4g+i>r); zero K rows give
    // score 0 -> e=1, V=0: denominator fixed analytically below.
    // paw k-slot map: key(g,j) = kb*32 + (j>>2)*16 + 4g + (j&3).
    u32x4 paw[5];
    float sum = 0.f;
    const int tg = 4 * g;
    #pragma unroll
    for (int kc = 0; kc < NKC; ++kc) {
        const int row = wv * 16 + kc * 16 + r;
        const bf16x8 ka0 = *(const bf16x8*)&sKp[row * 64 + ((g ^ rx) << 3)];
        const bf16x8 ka1 = *(const bf16x8*)&sKp[row * 64 + (((g + 4) ^ rx) << 3)];
        f32x4 c = {0.f, 0.f, 0.f, 0.f};
        c = __builtin_amdgcn_mfma_f32_16x16x32_bf16(ka0, qf0, c, 0, 0, 0);
        c = __builtin_amdgcn_mfma_f32_16x16x32_bf16(ka1, qf1, c, 0, 0, 0);
        f32x4 e;
        #pragma unroll
        for (int i = 0; i < 4; ++i) {
            float ev = exp2f(c[i]);   // scores already in log2 units
            if (kc == 0) ev = (tg + i >= r) ? ev : 0.f;
            if (kc == 8) ev = (tg + i <= r) ? ev : 0.f;
            e[i] = ev;
            sum += ev;
        }
        const uint32_t wlo = cvt_pk(e[0], e[1]);
        const uint32_t whi = cvt_pk(e[2], e[3]);
        if ((kc & 1) == 0) { paw[kc >> 1][0] = wlo; paw[kc >> 1][1] = whi; }
        else               { paw[kc >> 1][2] = wlo; paw[kc >> 1][3] = whi; }
    }
    paw[4][2] = 0; paw[4][3] = 0;

    sum += __shfl_xor(sum, 16);
    sum += __shfl_xor(sum, 32);
    const int oob = max(0, WHALF - qrow) + max(0, qrow - (SLEN - 1 - WHALF));
    const float inv = 1.f / (sum - (float)oob);

    __syncthreads();   // bar2: all K reads done; sbuf free for V

    // ========== phase 2: V staging, 3 jobs, STRICTLY SERIAL ==========
    // job j = tid + it*256: kp = j>>3 in [0,96), c8 = j&7 -> d = c8*8..+7.
    // ~16 regs live per job; TLP (24 waves) hides the load latency.
    #pragma unroll
    for (int it = 0; it < 3; ++it) {
        const int j = tid + it * 256;
        const int kp = j >> 3, dd = (j & 7) * 8;
        const int s0 = kstart + 2 * kp, s1 = s0 + 1;
        const f32x4 z = {0.f, 0.f, 0.f, 0.f};
        f32x4 va0 = z, va1 = z, vb0 = z, vb1 = z;
        if ((unsigned)s0 < SLEN) {
            const f32x4* g0 = (const f32x4*)(qkv +
                (((size_t)(b * SLEN + s0) * 3 + 2) * NHEAD + h) * HD + dd);
            va0 = g0[0]; va1 = g0[1];
        }
        if ((unsigned)s1 < SLEN) {
            const f32x4* g1 = (const f32x4*)(qkv +
                (((size_t)(b * SLEN + s1) * 3 + 2) * NHEAD + h) * HD + dd);
            vb0 = g1[0]; vb1 = g1[1];
        }
        u32x4 w0, w1;
        w0[0] = cvt_pk(va0[0], vb0[0]); w0[1] = cvt_pk(va0[1], vb0[1]);
        w0[2] = cvt_pk(va0[2], vb0[2]); w0[3] = cvt_pk(va0[3], vb0[3]);
        w1[0] = cvt_pk(va1[0], vb1[0]); w1[1] = cvt_pk(va1[1], vb1[1]);
        w1[2] = cvt_pk(va1[2], vb1[2]); w1[3] = cvt_pk(va1[3], vb1[3]);
        *(u32x4*)&sbuf[kp * VST + dd]     = w0;
        *(u32x4*)&sbuf[kp * VST + dd + 4] = w1;
    }
    __syncthreads();   // bar3: V staged

    // ================= O = P x V (paired-key u32 reads) =================
    // kb<4: keys kb*32 + {0,1,2,3,16,17,18,19} + 4g (pairs +0,+1,+8,+9).
    // kb=4: lo half only (hi pa==0 -> w[2]=w[3]=0, no LDS read; max kp=95).
    const uint32_t* vptr = &sbuf[(wv * 8 + 2 * g) * VST + r];
    f32x4 oacc[4] = {{0,0,0,0},{0,0,0,0},{0,0,0,0},{0,0,0,0}};
    #pragma unroll
    for (int kb = 0; kb < 5; ++kb) {
        const bf16x8 pa = __builtin_bit_cast(bf16x8, paw[kb]);
        #pragma unroll
        for (int dc = 0; dc < 4; ++dc) {
            const int base = kb * 16 * VST + dc * 16;
            u32x4 w;
            w[0] = vptr[base];                 // keys kb*32+4g, +1
            w[1] = vptr[base + VST];           // +2, +3
            if (kb < 4) {
                w[2] = vptr[base + 8 * VST];   // +16, +17
                w[3] = vptr[base + 9 * VST];   // +18, +19
            } else {
                w[2] = 0; w[3] = 0;            // pa hi == 0; avoid OOB read
            }
            const bf16x8 vbf = __builtin_bit_cast(bf16x8, w);
            oacc[dc] = __builtin_amdgcn_mfma_f32_16x16x32_bf16(pa, vbf, oacc[dc], 0, 0, 0);
        }
    }

    // ---- store (C row = query = g*4+i, col = d = r), deferred norm ----
    #pragma unroll
    for (int i = 0; i < 4; ++i) {
        const float iq = __shfl(inv, g * 4 + i);   // inv depends only on lane&15
        const int qg = q0 + wv * 16 + g * 4 + i;
        float* orow = out + (((size_t)(b * SLEN + qg)) * NHEAD + h) * HD + r;
        orow[0]  = oacc[0][i] * iq;
        orow[16] = oacc[1][i] * iq;
        orow[32] = oacc[2][i] * iq;
        orow[48] = oacc[3][i] * iq;
    }
}

extern "C" void kernel_launch(void* const* d_in, const int* in_sizes, int n_in,
                              void* d_out, int out_size, void* d_ws, size_t ws_size,
                              hipStream_t stream) {
    const float* qkv  = (const float*)d_in[0];
    const float* cosT = (const float*)d_in[1];
    const float* sinT = (const float*)d_in[2];
    // d_in[3] = mask: unused (band structure computed analytically)
    float* out = (float*)d_out;
    dim3 grid(32 * NHEAD * NBATCH);   // 1536 = 6 blocks/CU x 256 CUs, no tail
    dim3 block(256);
    hipLaunchKernelGGL(prokbert_attn, grid, block, 0, stream, qkv, cosT, sinT, out);
}